// Round 3
// baseline (3028.210 us; speedup 1.0000x reference)
//
#include <hip/hip_runtime.h>
#include <hip/hip_bf16.h>

// LCA sparsifier: 10 iterations of v = 0.9v + 0.1u - 0.1*(a@G); a = soft(v, lam)
// Fused persistent-row design: each block owns 64 rows across all 10 iterations.
// R2: u held in 32 packed-bf16 registers (not reloaded from HBM - R1's mistake,
// 1.34 GB refetch; not 64 f32 regs - R0's mistake, 1 block/CU). Persistent regs
// = 64 acc + 32 upk = 96 <= 128 @ launch_bounds(512,4) -> 2 blocks/CU, so one
// block's epilogue VALU overlaps the other block's MFMA (m114 co-scheduling).
// Gb re-laid out [ct][kk][lane]: B-loads stride 1KB -> immediate offsets, no
// per-load 64-bit address VALU in the K-loop.
// - acc registers double as v-state: C_init = -9v - u, after GEMM C = P-9v-u,
//   v_new = -0.1*C, next C_init = 0.9*C - u.
// - a round-trips through LDS as bf16 (A layout, stride 520 -> 0 bank conflicts).
// - soft(v) = v - med3(v, -lam, lam).

typedef __attribute__((ext_vector_type(8))) short bf16x8;
typedef __attribute__((ext_vector_type(16))) float f32x16;

#define ETA 0.1f

__device__ __forceinline__ unsigned f2bf_u(float f) {
  union { float f; unsigned u; } x; x.f = f;
  return (x.u + 0x8000u) >> 16;  // round-half-up, rel err <= 2^-9
}
__device__ __forceinline__ unsigned short f2bf(float f) {
  return (unsigned short)f2bf_u(f);
}
__device__ __forceinline__ float bf2f_lo(unsigned w) {
  union { unsigned u; float f; } x; x.u = w << 16; return x.f;
}
__device__ __forceinline__ float bf2f_hi(unsigned w) {
  union { unsigned u; float f; } x; x.u = w & 0xffff0000u; return x.f;
}

// ---- prep: G = 0.5(Graw + Graw^T), zero diag, bf16, swizzled into
// mfma_f32_32x32x16_bf16 B-fragment order, laid out [ct][kk][lane][j]:
// ct = n>>5 (col tile), kk = k>>4, lane = (n&31) + 32*((k>>3)&1), j = k&7.
__global__ void prep_G(const float* __restrict__ Graw, unsigned short* __restrict__ Gb) {
  int idx = blockIdx.x * blockDim.x + threadIdx.x;  // 512*512 elements
  int k = idx >> 9, n = idx & 511;
  float g = 0.5f * (Graw[k * 512 + n] + Graw[n * 512 + k]);
  if (k == n) g = 0.f;
  int ct = n >> 5, kk = k >> 4;
  int lane = (n & 31) + (((k >> 3) & 1) << 5);
  int j = k & 7;
  Gb[((((ct * 32 + kk) * 64) + lane) << 3) + j] = f2bf(g);
}

__global__ __launch_bounds__(512, 4) void lca_kernel(
    const float* __restrict__ u_g, const unsigned short* __restrict__ Gb,
    const float* __restrict__ log_lam, float* __restrict__ out) {
  // a-buffer: 64 rows x 512 cols bf16, row stride 520 -> conflict-free b128 reads.
  __shared__ unsigned short sA[64 * 520];

  const int tid = threadIdx.x;
  const int lane = tid & 63;
  const int wave = tid >> 6;           // 0..7, owns cols [wave*64, wave*64+64)
  const int R0 = blockIdx.x * 64;      // block's global row base
  const int cl = lane & 31;            // col within 32-tile / A-row within tile
  const int rquad = (lane >> 5) * 4;   // C-layout row contribution of lane-half
  const int C0 = wave * 64;

  const float lam = expf(log_lam[0]);

  f32x16 acc[2][2];    // C layout: col=lane&31, row=(reg&3)+8*(reg>>2)+4*(lane>>5)
  unsigned upk[2][2][8];  // u as packed bf16 pairs (regs 2j, 2j+1)

  // ---- t=0 fused init+epilogue: v1 = 0.1*u, a1 = soft(v1), acc = -9*v1 - u = -1.9u
  #pragma unroll
  for (int rt = 0; rt < 2; ++rt) {
    #pragma unroll
    for (int ctl = 0; ctl < 2; ++ctl) {
      const float* ub = u_g + (R0 + rt * 32 + rquad) * 512 + C0 + ctl * 32 + cl;
      unsigned short* sa = &sA[(rt * 32 + rquad) * 520 + C0 + ctl * 32 + cl];
      f32x16 tu;
      #pragma unroll
      for (int reg = 0; reg < 16; ++reg) {
        const int rofs = (reg & 3) + 8 * (reg >> 2);
        tu[reg] = ub[rofs * 512];
      }
      #pragma unroll
      for (int reg = 0; reg < 16; ++reg) {
        const int rofs = (reg & 3) + 8 * (reg >> 2);
        float v = ETA * tu[reg];
        float c = __builtin_amdgcn_fmed3f(v, -lam, lam);
        sa[rofs * 520] = f2bf(v - c);
        acc[rt][ctl][reg] = -1.9f * tu[reg];
      }
      #pragma unroll
      for (int j = 0; j < 8; ++j)
        upk[rt][ctl][j] = f2bf_u(tu[2 * j]) | (f2bf_u(tu[2 * j + 1]) << 16);
    }
  }
  __syncthreads();

  // A-fragment base: A[m][k], m = lane&31 (local row), k = kk*16 + (lane>>5)*8 + j
  const unsigned short* paRow = sA + cl * 520 + ((lane >> 5) << 3);
  const bf16x8* gb = (const bf16x8*)Gb;
  const bf16x8* gb0 = gb + wave * 4096 + lane;   // ct = 2*wave,   + kk*64
  const bf16x8* gb1 = gb0 + 2048;                // ct = 2*wave+1, + kk*64

  #pragma unroll 1
  for (int t = 1; t < 10; ++t) {
    #pragma unroll 4
    for (int kk = 0; kk < 32; ++kk) {
      bf16x8 a0 = *(const bf16x8*)(paRow + kk * 16);
      bf16x8 a1 = *(const bf16x8*)(paRow + 32 * 520 + kk * 16);
      bf16x8 b0 = gb0[kk * 64];
      bf16x8 b1 = gb1[kk * 64];
      acc[0][0] = __builtin_amdgcn_mfma_f32_32x32x16_bf16(a0, b0, acc[0][0], 0, 0, 0);
      acc[0][1] = __builtin_amdgcn_mfma_f32_32x32x16_bf16(a0, b1, acc[0][1], 0, 0, 0);
      acc[1][0] = __builtin_amdgcn_mfma_f32_32x32x16_bf16(a1, b0, acc[1][0], 0, 0, 0);
      acc[1][1] = __builtin_amdgcn_mfma_f32_32x32x16_bf16(a1, b1, acc[1][1], 0, 0, 0);
    }
    __syncthreads();  // all A-reads of this iteration done
    if (t < 9) {
      // epilogue: a_{t+1} = soft(-ETA*acc) -> LDS; acc = 0.9*acc - u (u from regs)
      #pragma unroll
      for (int rt = 0; rt < 2; ++rt) {
        #pragma unroll
        for (int ctl = 0; ctl < 2; ++ctl) {
          unsigned short* sa = &sA[(rt * 32 + rquad) * 520 + C0 + ctl * 32 + cl];
          #pragma unroll
          for (int reg = 0; reg < 16; ++reg) {
            const int rofs = (reg & 3) + 8 * (reg >> 2);
            float v = -ETA * acc[rt][ctl][reg];
            float c = __builtin_amdgcn_fmed3f(v, -lam, lam);
            sa[rofs * 520] = f2bf(v - c);
            unsigned w = upk[rt][ctl][reg >> 1];
            float uv = (reg & 1) ? bf2f_hi(w) : bf2f_lo(w);
            acc[rt][ctl][reg] = __builtin_fmaf(0.9f, acc[rt][ctl][reg], -uv);
          }
        }
      }
      __syncthreads();
    }
  }

  // ---- final output: a_10 = soft(-ETA * acc)
  #pragma unroll
  for (int rt = 0; rt < 2; ++rt) {
    #pragma unroll
    for (int ctl = 0; ctl < 2; ++ctl) {
      float* ob = out + (R0 + rt * 32 + rquad) * 512 + C0 + ctl * 32 + cl;
      #pragma unroll
      for (int reg = 0; reg < 16; ++reg) {
        const int rofs = (reg & 3) + 8 * (reg >> 2);
        float v = -ETA * acc[rt][ctl][reg];
        float c = __builtin_amdgcn_fmed3f(v, -lam, lam);
        ob[rofs * 512] = v - c;
      }
    }
  }
}

extern "C" void kernel_launch(void* const* d_in, const int* in_sizes, int n_in,
                              void* d_out, int out_size, void* d_ws, size_t ws_size,
                              hipStream_t stream) {
  const float* u = (const float*)d_in[0];
  const float* Graw = (const float*)d_in[1];
  const float* log_lam = (const float*)d_in[2];
  float* out = (float*)d_out;
  unsigned short* Gb = (unsigned short*)d_ws;  // 512*512*2 = 512 KB scratch

  prep_G<<<dim3(1024), dim3(256), 0, stream>>>(Graw, Gb);
  lca_kernel<<<dim3(1024), dim3(512), 0, stream>>>(u, Gb, log_lam, out);
}

// Round 4
// 543.840 us; speedup vs baseline: 5.5682x; 5.5682x over previous
//
#include <hip/hip_runtime.h>
#include <hip/hip_bf16.h>

// LCA sparsifier: 10 iterations of v = 0.9v + 0.1u - 0.1*(a@G); a = soft(v, lam)
// Fused persistent-row design: each block owns 64 rows across all 10 iterations.
// R3: back to R0's proven register layout (u in 64 f32 regs, 1 block/CU,
// launch_bounds(512,2) -> 256-reg budget, no spills; R2's (512,4) spilled ->
// 7.5 GB scratch traffic). New: DOUBLE-BUFFERED sA (2x66560=133KB LDS) -> ONE
// barrier per iteration; a wave's epilogue writes the other buffer right after
// its own GEMM, so the two waves/SIMD slide and VALU overlaps MFMA/LDS/L2.
// kk order staggered per block to decorrelate the identical L2 G-streams.
// - acc registers double as v-state: C_init = -9v - u, after GEMM C = P-9v-u,
//   v_new = -0.1*C, next C_init = 0.9*C - u (one FMA with nu=-u).
// - a round-trips through LDS as bf16 (A layout, stride 520 -> 0 bank conflicts).
// - G pre-swizzled to bf16 B-fragment order [ct][kk][lane][j] -> coalesced 16B L2 loads.
// - soft(v) = v - med3(v, -lam, lam).

typedef __attribute__((ext_vector_type(8))) short bf16x8;
typedef __attribute__((ext_vector_type(16))) float f32x16;

#define ETA 0.1f

__device__ __forceinline__ unsigned short f2bf(float f) {
  union { float f; unsigned u; } x; x.f = f;
  return (unsigned short)((x.u + 0x8000u) >> 16);  // round-half-up, rel err <= 2^-9
}

// ---- prep: G = 0.5(Graw + Graw^T), zero diag, bf16, swizzled into
// mfma_f32_32x32x16_bf16 B-fragment order, laid out [ct][kk][lane][j]:
// ct = n>>5 (col tile), kk = k>>4, lane = (n&31) + 32*((k>>3)&1), j = k&7.
__global__ void prep_G(const float* __restrict__ Graw, unsigned short* __restrict__ Gb) {
  int idx = blockIdx.x * blockDim.x + threadIdx.x;  // 512*512 elements
  int k = idx >> 9, n = idx & 511;
  float g = 0.5f * (Graw[k * 512 + n] + Graw[n * 512 + k]);
  if (k == n) g = 0.f;
  int ct = n >> 5, kk = k >> 4;
  int lane = (n & 31) + (((k >> 3) & 1) << 5);
  int j = k & 7;
  Gb[((((ct * 32 + kk) * 64) + lane) << 3) + j] = f2bf(g);
}

__global__ __launch_bounds__(512, 2) void lca_kernel(
    const float* __restrict__ u_g, const unsigned short* __restrict__ Gb,
    const float* __restrict__ log_lam, float* __restrict__ out) {
  // Double-buffered a-matrix: 2 x (64 rows x 520-stride) bf16.
  // Stride 520 -> b128 A-fragment reads are bank-conflict-free (measured R0-R2: 0).
  __shared__ unsigned short sA[2][64 * 520];

  const int tid = threadIdx.x;
  const int lane = tid & 63;
  const int wave = tid >> 6;           // 0..7, owns cols [wave*64, wave*64+64)
  const int Rb = blockIdx.x * 64;      // block's global row base
  const int cl = lane & 31;            // col within 32-tile / A-row within tile
  const int rquad = (lane >> 5) * 4;   // C-layout row contribution of lane-half
  const int C0 = wave * 64;

  const float lam = expf(log_lam[0]);

  f32x16 acc[2][2];  // C layout: col=lane&31, row=(reg&3)+8*(reg>>2)+4*(lane>>5)
  f32x16 nu[2][2];   // -u, persistent (fits: ~84 arch VGPR + 128 AGPR @ 2 waves/EU)

  // ---- t=0 fused init+epilogue: v1 = 0.1*u, a1 = soft(v1) -> buf0, acc = -1.9u
  #pragma unroll
  for (int rt = 0; rt < 2; ++rt) {
    #pragma unroll
    for (int ctl = 0; ctl < 2; ++ctl) {
      const float* ub = u_g + (Rb + rt * 32 + rquad) * 512 + C0 + ctl * 32 + cl;
      unsigned short* sa = &sA[0][(rt * 32 + rquad) * 520 + C0 + ctl * 32 + cl];
      f32x16 tu;
      #pragma unroll
      for (int reg = 0; reg < 16; ++reg) {
        const int rofs = (reg & 3) + 8 * (reg >> 2);
        tu[reg] = ub[rofs * 512];
      }
      #pragma unroll
      for (int reg = 0; reg < 16; ++reg) {
        const int rofs = (reg & 3) + 8 * (reg >> 2);
        float v = ETA * tu[reg];
        float c = __builtin_amdgcn_fmed3f(v, -lam, lam);
        sa[rofs * 520] = f2bf(v - c);
        acc[rt][ctl][reg] = -1.9f * tu[reg];
        nu[rt][ctl][reg] = -tu[reg];
      }
    }
  }
  __syncthreads();

  // A-fragment base: A[m][k], m = lane&31 (local row), k = kk*16 + (lane>>5)*8 + j
  const unsigned short* paRow = &sA[0][0] + cl * 520 + ((lane >> 5) << 3);
  unsigned short* swBase = &sA[0][0] + rquad * 520 + C0 + cl;
  const bf16x8* gb0 = (const bf16x8*)Gb + wave * 4096 + lane;  // ct=2w,   +kk*64
  const bf16x8* gb1 = gb0 + 2048;                              // ct=2w+1, +kk*64
  const int rot = (blockIdx.x & 3) << 3;  // stagger kk chunks across blocks

  #pragma unroll 1
  for (int t = 1; t < 10; ++t) {
    // GEMM t reads a_t from buf[(t+1)&1] (a1 in buf0, a2 in buf1, ...)
    const unsigned short* pa = paRow + ((t + 1) & 1) * (64 * 520);
    #pragma unroll 4
    for (int kki = 0; kki < 32; ++kki) {
      const int kk = kki ^ rot;  // affine within unroll-4 chunks (rot is mult of 8)
      bf16x8 a0 = *(const bf16x8*)(pa + kk * 16);
      bf16x8 a1 = *(const bf16x8*)(pa + 32 * 520 + kk * 16);
      bf16x8 b0 = gb0[kk * 64];
      bf16x8 b1 = gb1[kk * 64];
      acc[0][0] = __builtin_amdgcn_mfma_f32_32x32x16_bf16(a0, b0, acc[0][0], 0, 0, 0);
      acc[0][1] = __builtin_amdgcn_mfma_f32_32x32x16_bf16(a0, b1, acc[0][1], 0, 0, 0);
      acc[1][0] = __builtin_amdgcn_mfma_f32_32x32x16_bf16(a1, b0, acc[1][0], 0, 0, 0);
      acc[1][1] = __builtin_amdgcn_mfma_f32_32x32x16_bf16(a1, b1, acc[1][1], 0, 0, 0);
    }
    if (t < 9) {
      // epilogue (no barrier needed first: writes go to the OTHER buffer):
      // a_{t+1} = soft(-ETA*acc) -> buf[t&1]; acc = 0.9*acc - u
      unsigned short* sw = swBase + (t & 1) * (64 * 520);
      #pragma unroll
      for (int rt = 0; rt < 2; ++rt) {
        #pragma unroll
        for (int ctl = 0; ctl < 2; ++ctl) {
          unsigned short* sa = sw + (rt * 32) * 520 + ctl * 32;
          #pragma unroll
          for (int reg = 0; reg < 16; ++reg) {
            const int rofs = (reg & 3) + 8 * (reg >> 2);
            float a = acc[rt][ctl][reg];
            float v = -ETA * a;
            float c = __builtin_amdgcn_fmed3f(v, -lam, lam);
            sa[rofs * 520] = f2bf(v - c);
            acc[rt][ctl][reg] = __builtin_fmaf(0.9f, a, nu[rt][ctl][reg]);
          }
        }
      }
    }
    // ONE barrier per iteration: after it, everyone's GEMM-t reads and
    // epilogue-t writes are done -> next GEMM may read buf[t&1], and the
    // next epilogue may overwrite buf[(t+1)&1].
    __syncthreads();
  }

  // ---- final output: a_10 = soft(-ETA * acc)
  #pragma unroll
  for (int rt = 0; rt < 2; ++rt) {
    #pragma unroll
    for (int ctl = 0; ctl < 2; ++ctl) {
      float* ob = out + (Rb + rt * 32 + rquad) * 512 + C0 + ctl * 32 + cl;
      #pragma unroll
      for (int reg = 0; reg < 16; ++reg) {
        const int rofs = (reg & 3) + 8 * (reg >> 2);
        float v = -ETA * acc[rt][ctl][reg];
        float c = __builtin_amdgcn_fmed3f(v, -lam, lam);
        ob[rofs * 512] = v - c;
      }
    }
  }
}

extern "C" void kernel_launch(void* const* d_in, const int* in_sizes, int n_in,
                              void* d_out, int out_size, void* d_ws, size_t ws_size,
                              hipStream_t stream) {
  const float* u = (const float*)d_in[0];
  const float* Graw = (const float*)d_in[1];
  const float* log_lam = (const float*)d_in[2];
  float* out = (float*)d_out;
  unsigned short* Gb = (unsigned short*)d_ws;  // 512*512*2 = 512 KB scratch

  prep_G<<<dim3(1024), dim3(256), 0, stream>>>(Graw, Gb);
  lca_kernel<<<dim3(1024), dim3(512), 0, stream>>>(u, Gb, log_lam, out);
}